// Round 9
// baseline (458.414 us; speedup 1.0000x reference)
//
#include <hip/hip_runtime.h>
#include <math.h>

#define NQ 4096
#define NT 16384
#define DD 32
#define COLIDX 0
#define BIGF 1.0e10f
#define INFF __builtin_inff()

typedef unsigned long long u64;

#define ROW_VECS (NT / 4)                 // 4096 float4 per row
#define ROWS_PER_BLOCK 4
#define P1_BLOCKS (NQ / ROWS_PER_BLOCK)   // 1024 = 4 blocks/CU exactly

// ---------------------------------------------------------------------------
// bool-width helpers (unknown numpy bool storage: u8 vs i32)
// ---------------------------------------------------------------------------
__device__ __forceinline__ int boolat(const void* p, long long idx, int w32) {
    if (w32) return ((const int*)p)[idx] != 0;
    return ((const unsigned char*)p)[idx] != 0;
}

__device__ __forceinline__ int detect_w32(const void* nm, const void* mk,
                                          int tid, int* s_bad) {
    if (tid == 0) *s_bad = 0;
    __syncthreads();
    const unsigned char* nm8 = (const unsigned char*)nm;
    const unsigned char* mk8 = (const unsigned char*)mk;
    int bad = 0;
    for (int b = tid; b < 4096; b += 256)
        if ((int)nm8[b] + (int)mk8[b] != 1) bad = 1;
    if (bad) atomicOr(s_bad, 1);
    __syncthreads();
    return *s_bad ? 1 : 0;
}

// ---------------------------------------------------------------------------
// prep1: 64 blocks x 256 threads — pot8 + pen pack, colmean partials,
// inmiss clear.
// ---------------------------------------------------------------------------
__global__ __launch_bounds__(256) void prep1_kernel(
    const void* __restrict__ nm, const void* __restrict__ mk,
    const float* __restrict__ fitX,
    int* __restrict__ wflag, float* __restrict__ partial,
    unsigned char* __restrict__ inmiss, unsigned char* __restrict__ pot8,
    float* __restrict__ pen)
{
    __shared__ int s_bad;
    __shared__ float sc[256], sm[256];
    const int tid = threadIdx.x;
    const int w32 = detect_w32(nm, mk, tid, &s_bad);
    if (blockIdx.x == 0 && tid == 0) *wflag = w32;

    const int t = blockIdx.x * 256 + tid;          // 0..16383
    const int pot = boolat(nm, (long long)t * DD + COLIDX, w32);
    pot8[t] = (unsigned char)pot;
    pen[t]  = pot ? 0.0f : INFF;

    float cs = 0.0f, ms = 0.0f;
    if (!boolat(mk, (long long)t * DD + COLIDX, w32)) {
        cs = fitX[(long long)t * DD + COLIDX];
        ms = 1.0f;
    }
    sc[tid] = cs; sm[tid] = ms;
    __syncthreads();
#pragma unroll
    for (int s = 128; s > 0; s >>= 1) {
        if (tid < s) { sc[tid] += sc[tid + s]; sm[tid] += sm[tid + s]; }
        __syncthreads();
    }
    if (tid == 0) { partial[blockIdx.x * 2] = sc[0]; partial[blockIdx.x * 2 + 1] = sm[0]; }

    if (t < NQ) inmiss[t] = 0;
}

__global__ __launch_bounds__(256) void prep2_kernel(
    const int* __restrict__ rmi, const float* __restrict__ partial,
    float* __restrict__ cmean, unsigned char* __restrict__ inmiss)
{
    const int tid = threadIdx.x;
    for (int i = tid; i < NQ; i += 256) {
        int r = rmi[i];
        if (r >= 0 && r < NQ) inmiss[r] = 1;
    }
    if (tid == 0) {
        float c = 0.0f, m = 0.0f;
        for (int b = 0; b < 64; ++b) { c += partial[2 * b]; m += partial[2 * b + 1]; }
        *cmean = c / (m > 0.0f ? m : 1.0f);
    }
}

// ---------------------------------------------------------------------------
// f32 key-only network primitives (keys never NaN: fmin removes NaN, +pen
// keeps finite/INF). casf = v_min + v_max = 2 VALU (vs 5 for u64).
// Multiset top-5 semantics are exact; indices recovered by rescan.
// ---------------------------------------------------------------------------
__device__ __forceinline__ void casf(float& x, float& y) {
    const float lo = fminf(x, y);
    const float hi = fmaxf(x, y);
    x = lo; y = hi;
}

// Merge ascending sorted-5 'a' with ascending sorted-5 'b', keep lowest 5.
// Half-cleaner -> mountain -> pruned bitonic cleanup (validated rounds 6-8).
__device__ __forceinline__ void merge5f(float a[5], const float b[5]) {
    float m0 = fminf(a[0], b[4]);
    float m1 = fminf(a[1], b[3]);
    float m2 = fminf(a[2], b[2]);
    float m3 = fminf(a[3], b[1]);
    float m4 = fminf(a[4], b[0]);
    casf(m0, m4);
    casf(m1, m3); casf(m2, m4);
    casf(m1, m2); casf(m3, m4);
    a[0] = m0; a[1] = m1; a[2] = m2; a[3] = m3; a[4] = m4;
}

// exact u64 (key,idx) insert — used only on the tiny candidate tail
__device__ __forceinline__ void insert64(u64 k, u64 v[5]) {
    const bool c0 = k < v[0];
    const bool c1 = k < v[1];
    const bool c2 = k < v[2];
    const bool c3 = k < v[3];
    const bool c4 = k < v[4];
    v[4] = c4 ? (c3 ? v[3] : k) : v[4];
    v[3] = c3 ? (c2 ? v[2] : k) : v[3];
    v[2] = c2 ? (c1 ? v[1] : k) : v[2];
    v[1] = c1 ? (c0 ? v[0] : k) : v[1];
    v[0] = c0 ? k : v[0];
}

// ---------------------------------------------------------------------------
// Pass 1: 4 rows per block, 1024 blocks (fully resident: 4 blocks/CU).
// Phase A: f32-key scan, thread keeps its 64 keys in regs; sort4 + merge-5
//   networks (~8 VALU/elem). Butterfly + LDS -> exact 5th-smallest key thr.
// Phase B: rescan k[] vs thr: tier A (k<thr, <=4/row, exact) + tier B
//   (k==thr, per-wave idx-ordered, cap 8). tid0 rebuilds exact (key,idx)
//   top-5 via insert64 and writes 5 u64 per row.
// ---------------------------------------------------------------------------
__global__ __launch_bounds__(256, 4) void pass1_kernel(
    const float* __restrict__ dist,
    const float* __restrict__ pen,
    u64* __restrict__ wslists)
{
    __shared__ float sv[4][5];
    __shared__ u64 ldsA[8];
    __shared__ unsigned ldsB[4][8];
    __shared__ int ldsAcnt;
    __shared__ int ldsBcnt[4];

    const int tid  = threadIdx.x;
    const int lane = tid & 63;
    const int wave = tid >> 6;
    const u64 lt_mask = (lane == 0) ? 0ull : (~0ull >> (64 - lane));
    const float4* pen4 = (const float4*)pen;

#pragma unroll 1
    for (int rr = 0; rr < ROWS_PER_BLOCK; ++rr) {
        const int row = blockIdx.x * ROWS_PER_BLOCK + rr;
        const float4* dvec = (const float4*)dist + (long long)row * ROW_VECS;

        if (tid == 0) ldsAcnt = 0;
        if (tid < 4) ldsBcnt[tid] = 0;

        float k[64];
        float v[5];
#pragma unroll
        for (int i = 0; i < 5; ++i) v[i] = INFF;

        // ---- Phase A: scan (keys stay in registers) ----
#pragma unroll
        for (int half = 0; half < 4; ++half) {
            float4 dd[4]; float4 pq[4];
#pragma unroll
            for (int g = 0; g < 4; ++g) {
                const int vi = (half * 4 + g) * 256 + tid;
                dd[g] = dvec[vi];
                pq[g] = pen4[vi];
            }
#pragma unroll
            for (int g = 0; g < 4; ++g) {
                const int base = (half * 4 + g) * 4;
                float s0 = fminf(dd[g].x, BIGF) + pq[g].x;  // NaN->BIG; !pot->INF
                float s1 = fminf(dd[g].y, BIGF) + pq[g].y;
                float s2 = fminf(dd[g].z, BIGF) + pq[g].z;
                float s3 = fminf(dd[g].w, BIGF) + pq[g].w;
                k[base + 0] = s0; k[base + 1] = s1;
                k[base + 2] = s2; k[base + 3] = s3;
                // sort4: (0,1)(2,3)(0,2)(1,3)(1,2)
                casf(s0, s1); casf(s2, s3);
                casf(s0, s2); casf(s1, s3);
                casf(s1, s2);
                // merge sorted-4 (MAX pad) into running sorted-5
                float m0 = v[0];
                float m1 = fminf(v[1], s3);
                float m2 = fminf(v[2], s2);
                float m3 = fminf(v[3], s1);
                float m4 = fminf(v[4], s0);
                casf(m0, m4);
                casf(m1, m3); casf(m2, m4);
                casf(m1, m2); casf(m3, m4);
                v[0] = m0; v[1] = m1; v[2] = m2; v[3] = m3; v[4] = m4;
            }
        }

        // ---- wave butterfly (f32) ----
#pragma unroll
        for (int mask = 1; mask <= 32; mask <<= 1) {
            float b[5];
#pragma unroll
            for (int i = 0; i < 5; ++i) b[i] = __shfl_xor(v[i], mask, 64);
            merge5f(v, b);
        }
        // cross-wave: every thread rebuilds the block list (thr in-register)
        if (lane == 0) {
#pragma unroll
            for (int i = 0; i < 5; ++i) sv[wave][i] = v[i];
        }
        __syncthreads();
        {
            float acc[5], b[5];
#pragma unroll
            for (int i = 0; i < 5; ++i) acc[i] = sv[0][i];
#pragma unroll
            for (int w = 1; w < 4; ++w) {
#pragma unroll
                for (int i = 0; i < 5; ++i) b[i] = sv[w][i];
                merge5f(acc, b);
            }
            v[4] = acc[4];   // thr; acc[0..3] not needed further
        }
        const float thr = v[4];

        // ---- Phase B: rescan registers, collect candidates ----
        int cntB = 0;  // wave-uniform running count of ==thr matches
#pragma unroll
        for (int G = 0; G < 16; ++G) {
#pragma unroll
            for (int j = 0; j < 4; ++j) {
                const float kk = k[G * 4 + j];
                const u64 bb = __ballot(kk <= thr);
                if (bb) {                              // rare (~6 hits/row)
                    const u64 bA = __ballot(kk < thr);
                    const u64 bB = bb & ~bA;
                    if (kk <= thr) {
                        const unsigned idx = (unsigned)(G * 1024 + tid * 4 + j);
                        if (kk < thr) {                // tier A: exact, <=4/row
                            const int s = atomicAdd(&ldsAcnt, 1);
                            if (s < 8)
                                ldsA[s] = ((u64)__float_as_uint(kk) << 32) | (u64)idx;
                        } else {                       // tier B: ==thr, idx-ordered
                            const int s = cntB + (int)__popcll(bB & lt_mask);
                            if (s < 8) ldsB[wave][s] = idx;
                        }
                    }
                    cntB += (int)__popcll(bB);
                }
            }
        }
        if (lane == 0) ldsBcnt[wave] = cntB;
        __syncthreads();

        // ---- exact (key,idx) reconstruction on tid 0 ----
        if (tid == 0) {
            u64 out5[5];
#pragma unroll
            for (int i = 0; i < 5; ++i) out5[i] = 0xFFFFFFFFFFFFFFFFULL;
            const int ca = ldsAcnt < 8 ? ldsAcnt : 8;   // provably <=4
            for (int s = 0; s < ca; ++s) insert64(ldsA[s], out5);
            const u64 thrbits = ((u64)__float_as_uint(thr)) << 32;
            for (int w = 0; w < 4; ++w) {
                const int cb = ldsBcnt[w] < 8 ? ldsBcnt[w] : 8;
                for (int s = 0; s < cb; ++s)
                    insert64(thrbits | (u64)ldsB[w][s], out5);
            }
#pragma unroll
            for (int i = 0; i < 5; ++i)
                wslists[(long long)row * 5 + i] = out5[i];
        }
        __syncthreads();   // LDS reused next row
    }
}

// ---------------------------------------------------------------------------
// Pass 2 (fused): coalesced float4 copy of X->out; the lane owning each
// row's first float4 runs the epilogue (validated rounds 6-8) and patches .x.
// ---------------------------------------------------------------------------
__global__ __launch_bounds__(256) void pass2_kernel(
    const float* __restrict__ X,
    const u64* __restrict__ wslists,
    const void* __restrict__ maskp,
    const void* __restrict__ mkfitp,
    const float* __restrict__ fitX,
    const int* __restrict__ dmap,
    const int* __restrict__ wflagp,
    const float* __restrict__ cmeanp,
    const unsigned char* __restrict__ inmiss,
    const unsigned char* __restrict__ pot8,
    float* __restrict__ out)
{
    const int gid = blockIdx.x * 256 + threadIdx.x;    // 0..32767
    if (gid >= NQ * DD / 4) return;
    float4 v4 = ((const float4*)X)[gid];

    if ((gid & 7) == 0) {
        const int r = gid >> 3;
        const int q = dmap[r];
        u64 v[5];
        const u64* lp = wslists + (long long)q * 5;
#pragma unroll
        for (int i = 0; i < 5; ++i) v[i] = lp[i];

        const int w32 = *wflagp;
        const bool has_valid = (unsigned)(v[0] >> 32) < __float_as_uint(BIGF);
        const bool receiver =
            inmiss[r] && boolat(maskp, (long long)r * DD + COLIDX, w32);

        float val;
        if (!receiver) {
            val = v4.x;                    // X[r*DD+0]
        } else if (!has_valid) {
            val = *cmeanp;
        } else {
            float keyf[5]; bool ok[5]; int idxc[5];
#pragma unroll
            for (int i = 0; i < 5; ++i) {
                keyf[i] = __uint_as_float((unsigned)(v[i] >> 32));
                const unsigned id = (unsigned)(v[i] & 0xFFFFFFFFu);
                ok[i] = id < NT;
                idxc[i] = ok[i] ? (int)id : 0;
            }
            float dnr[5]; int mfv[5]; unsigned char vldb[5];
#pragma unroll
            for (int i = 0; i < 5; ++i)
                dnr[i] = fitX[(long long)idxc[i] * DD + COLIDX];
#pragma unroll
            for (int i = 0; i < 5; ++i)
                mfv[i] = boolat(mkfitp, (long long)idxc[i] * DD + COLIDX, w32);
#pragma unroll
            for (int i = 0; i < 5; ++i) vldb[i] = pot8[idxc[i]];

            float wk[5];
            bool infrow = false;
#pragma unroll
            for (int i = 0; i < 5; ++i) {
                const float dpot = (keyf[i] == BIGF) ? __builtin_nanf("") : keyf[i];
                const float t = 1.0f / dpot;     // 0->inf, inf->0, NaN->NaN
                wk[i] = ok[i] ? t : 0.0f;
                if (ok[i] && isinf(t)) infrow = true;
            }
            if (infrow) {
#pragma unroll
                for (int i = 0; i < 5; ++i) wk[i] = isinf(wk[i]) ? 1.0f : 0.0f;
            }
#pragma unroll
            for (int i = 0; i < 5; ++i) if (wk[i] != wk[i]) wk[i] = 0.0f;

            float wsum = 0.0f, vsum = 0.0f;
#pragma unroll
            for (int i = 0; i < 5; ++i) {
                const float dm = ok[i] ? (1.0f - (float)mfv[i]) : 0.0f;
                const float vl = ok[i] ? (float)vldb[i] : 0.0f;
                const float nw = dm * wk[i] * vl;
                wsum += nw;
                vsum += dnr[i] * nw;
            }
            const float div = (wsum == 0.0f) ? 1.0f : wsum;
            val = vsum / div;
        }
        v4.x = val;
    }
    ((float4*)out)[gid] = v4;
}

extern "C" void kernel_launch(void* const* d_in, const int* in_sizes, int n_in,
                              void* d_out, int out_size, void* d_ws, size_t ws_size,
                              hipStream_t stream) {
    const float* X     = (const float*)d_in[0];
    const float* dist  = (const float*)d_in[1];
    const void*  nm    = d_in[2];   // non_missing_fix_X (bool)
    const void*  mkfit = d_in[3];   // mask_fit_X (bool)
    const int*   dmap  = (const int*)d_in[4];
    const void*  maskp = d_in[5];   // mask (bool)
    const int*   rmi   = (const int*)d_in[6];
    const float* fitX  = (const float*)d_in[7];
    float* out = (float*)d_out;

    // workspace layout (all 4-byte aligned)
    u64*   wslists = (u64*)d_ws;                               // 4096*40 B
    char*  base    = (char*)d_ws + (size_t)NQ * 5 * 8;
    int*   wflag   = (int*)base;
    float* cmean   = (float*)(base + 4);
    float* partial = (float*)(base + 8);                       // 512 B
    unsigned char* inmiss = (unsigned char*)base + 520;        // NQ bytes
    unsigned char* pot8   = (unsigned char*)base + 520 + NQ;   // NT bytes
    float* pen = (float*)(base + 520 + NQ + NT);               // NT floats (64 KB)

    prep1_kernel<<<64, 256, 0, stream>>>(nm, mkfit, fitX, wflag, partial,
                                         inmiss, pot8, pen);
    prep2_kernel<<<1, 256, 0, stream>>>(rmi, partial, cmean, inmiss);
    pass1_kernel<<<P1_BLOCKS, 256, 0, stream>>>(dist, pen, wslists);
    pass2_kernel<<<(NQ * DD / 4 + 255) / 256, 256, 0, stream>>>(
        X, wslists, maskp, mkfit, fitX, dmap, wflag, cmean, inmiss, pot8, out);
}

// Round 10
// 171.798 us; speedup vs baseline: 2.6683x; 2.6683x over previous
//
#include <hip/hip_runtime.h>
#include <math.h>

#define NQ 4096
#define NT 16384
#define DD 32
#define COLIDX 0
#define BIGF 1.0e10f
#define INFF __builtin_inff()

typedef unsigned long long u64;

#define ROW_VECS (NT / 4)                 // 4096 float4 per row
#define ROWS_PER_BLOCK 2
#define P1_BLOCKS (NQ / ROWS_PER_BLOCK)   // 2048 blocks, fully resident

// ---------------------------------------------------------------------------
// bool-width helpers (unknown numpy bool storage: u8 vs i32)
// ---------------------------------------------------------------------------
__device__ __forceinline__ int boolat(const void* p, long long idx, int w32) {
    if (w32) return ((const int*)p)[idx] != 0;
    return ((const unsigned char*)p)[idx] != 0;
}

__device__ __forceinline__ int detect_w32(const void* nm, const void* mk,
                                          int tid, int* s_bad) {
    if (tid == 0) *s_bad = 0;
    __syncthreads();
    const unsigned char* nm8 = (const unsigned char*)nm;
    const unsigned char* mk8 = (const unsigned char*)mk;
    int bad = 0;
    for (int b = tid; b < 4096; b += 256)
        if ((int)nm8[b] + (int)mk8[b] != 1) bad = 1;
    if (bad) atomicOr(s_bad, 1);
    __syncthreads();
    return *s_bad ? 1 : 0;
}

// ---------------------------------------------------------------------------
// prep1: 64 blocks x 256 threads — pot8 + pen pack, colmean partials,
// inmiss clear.
// ---------------------------------------------------------------------------
__global__ __launch_bounds__(256) void prep1_kernel(
    const void* __restrict__ nm, const void* __restrict__ mk,
    const float* __restrict__ fitX,
    int* __restrict__ wflag, float* __restrict__ partial,
    unsigned char* __restrict__ inmiss, unsigned char* __restrict__ pot8,
    float* __restrict__ pen)
{
    __shared__ int s_bad;
    __shared__ float sc[256], sm[256];
    const int tid = threadIdx.x;
    const int w32 = detect_w32(nm, mk, tid, &s_bad);
    if (blockIdx.x == 0 && tid == 0) *wflag = w32;

    const int t = blockIdx.x * 256 + tid;          // 0..16383
    const int pot = boolat(nm, (long long)t * DD + COLIDX, w32);
    pot8[t] = (unsigned char)pot;
    pen[t]  = pot ? 0.0f : INFF;

    float cs = 0.0f, ms = 0.0f;
    if (!boolat(mk, (long long)t * DD + COLIDX, w32)) {
        cs = fitX[(long long)t * DD + COLIDX];
        ms = 1.0f;
    }
    sc[tid] = cs; sm[tid] = ms;
    __syncthreads();
#pragma unroll
    for (int s = 128; s > 0; s >>= 1) {
        if (tid < s) { sc[tid] += sc[tid + s]; sm[tid] += sm[tid + s]; }
        __syncthreads();
    }
    if (tid == 0) { partial[blockIdx.x * 2] = sc[0]; partial[blockIdx.x * 2 + 1] = sm[0]; }

    if (t < NQ) inmiss[t] = 0;
}

__global__ __launch_bounds__(256) void prep2_kernel(
    const int* __restrict__ rmi, const float* __restrict__ partial,
    float* __restrict__ cmean, unsigned char* __restrict__ inmiss)
{
    const int tid = threadIdx.x;
    for (int i = tid; i < NQ; i += 256) {
        int r = rmi[i];
        if (r >= 0 && r < NQ) inmiss[r] = 1;
    }
    if (tid == 0) {
        float c = 0.0f, m = 0.0f;
        for (int b = 0; b < 64; ++b) { c += partial[2 * b]; m += partial[2 * b + 1]; }
        *cmean = c / (m > 0.0f ? m : 1.0f);
    }
}

// ---------------------------------------------------------------------------
// f32 key-only network primitives (keys never NaN: fmin removes NaN, +pen
// keeps finite/INF). casf = v_min + v_max = 2 VALU.
// ---------------------------------------------------------------------------
__device__ __forceinline__ void casf(float& x, float& y) {
    const float lo = fminf(x, y);
    const float hi = fmaxf(x, y);
    x = lo; y = hi;
}

// Merge ascending sorted-5 'a' with sorted-5 'b', keep lowest 5 (validated).
__device__ __forceinline__ void merge5f(float a[5], const float b[5]) {
    float m0 = fminf(a[0], b[4]);
    float m1 = fminf(a[1], b[3]);
    float m2 = fminf(a[2], b[2]);
    float m3 = fminf(a[3], b[1]);
    float m4 = fminf(a[4], b[0]);
    casf(m0, m4);
    casf(m1, m3); casf(m2, m4);
    casf(m1, m2); casf(m3, m4);
    a[0] = m0; a[1] = m1; a[2] = m2; a[3] = m3; a[4] = m4;
}

// exact u64 (key,idx) insert — used only on the tiny candidate tail
__device__ __forceinline__ void insert64(u64 k, u64 v[5]) {
    const bool c0 = k < v[0];
    const bool c1 = k < v[1];
    const bool c2 = k < v[2];
    const bool c3 = k < v[3];
    const bool c4 = k < v[4];
    v[4] = c4 ? (c3 ? v[3] : k) : v[4];
    v[3] = c3 ? (c2 ? v[2] : k) : v[3];
    v[2] = c2 ? (c1 ? v[1] : k) : v[2];
    v[1] = c1 ? (c0 ? v[0] : k) : v[1];
    v[0] = c0 ? k : v[0];
}

// ---------------------------------------------------------------------------
// Pass 1: 2 rows per block, 2048 blocks (fully resident at 8 blocks/CU).
// Phase A: f32-key scan in 4 batches of 4 float4 (live set ~60 VGPR, NO
//   per-thread key array — round-9 spill lesson). sort4+merge-5 networks.
//   Butterfly + LDS -> exact 5th-smallest key thr.
// Phase B: RE-READ the row (same addresses -> L2/L3 hit, no extra HBM),
//   recompute keys bit-identically, collect tier A (k<thr, exact, <=4) and
//   tier B (k==thr, per-wave idx-ordered, cap 8; ties beyond are INF/BIG
//   weight-zero or measure-zero finite dups — validated round 9, absmax 0).
// tid0 rebuilds exact (key,idx) top-5 via insert64, writes 5 u64 per row.
// ---------------------------------------------------------------------------
__global__ __launch_bounds__(256) void pass1_kernel(
    const float* __restrict__ dist,
    const float* __restrict__ pen,
    u64* __restrict__ wslists)
{
    __shared__ float sv[4][5];
    __shared__ u64 ldsA[8];
    __shared__ unsigned ldsB[4][8];
    __shared__ int ldsAcnt;
    __shared__ int ldsBcnt[4];

    const int tid  = threadIdx.x;
    const int lane = tid & 63;
    const int wave = tid >> 6;
    const u64 lt_mask = (lane == 0) ? 0ull : (~0ull >> (64 - lane));
    const float4* pen4 = (const float4*)pen;

#pragma unroll 1
    for (int rr = 0; rr < ROWS_PER_BLOCK; ++rr) {
        const int row = blockIdx.x * ROWS_PER_BLOCK + rr;
        const float4* dvec = (const float4*)dist + (long long)row * ROW_VECS;

        if (tid == 0) ldsAcnt = 0;
        if (tid < 4) ldsBcnt[tid] = 0;

        float v[5];
#pragma unroll
        for (int i = 0; i < 5; ++i) v[i] = INFF;

        // ---- Phase A: scan; keys NOT stored (recomputed in phase B) ----
#pragma unroll 1
        for (int half = 0; half < 4; ++half) {
            float4 dd[4]; float4 pq[4];
#pragma unroll
            for (int g = 0; g < 4; ++g) {
                const int vi = (half * 4 + g) * 256 + tid;
                dd[g] = dvec[vi];
                pq[g] = pen4[vi];
            }
#pragma unroll
            for (int g = 0; g < 4; ++g) {
                float s0 = fminf(dd[g].x, BIGF) + pq[g].x;  // NaN->BIG; !pot->INF
                float s1 = fminf(dd[g].y, BIGF) + pq[g].y;
                float s2 = fminf(dd[g].z, BIGF) + pq[g].z;
                float s3 = fminf(dd[g].w, BIGF) + pq[g].w;
                // sort4: (0,1)(2,3)(0,2)(1,3)(1,2)
                casf(s0, s1); casf(s2, s3);
                casf(s0, s2); casf(s1, s3);
                casf(s1, s2);
                // merge sorted-4 (MAX pad) into running sorted-5
                float m0 = v[0];
                float m1 = fminf(v[1], s3);
                float m2 = fminf(v[2], s2);
                float m3 = fminf(v[3], s1);
                float m4 = fminf(v[4], s0);
                casf(m0, m4);
                casf(m1, m3); casf(m2, m4);
                casf(m1, m2); casf(m3, m4);
                v[0] = m0; v[1] = m1; v[2] = m2; v[3] = m3; v[4] = m4;
            }
        }

        // ---- wave butterfly (f32) ----
#pragma unroll
        for (int mask = 1; mask <= 32; mask <<= 1) {
            float b[5];
#pragma unroll
            for (int i = 0; i < 5; ++i) b[i] = __shfl_xor(v[i], mask, 64);
            merge5f(v, b);
        }
        if (lane == 0) {
#pragma unroll
            for (int i = 0; i < 5; ++i) sv[wave][i] = v[i];
        }
        __syncthreads();
        float thr;
        {
            float acc[5], b[5];
#pragma unroll
            for (int i = 0; i < 5; ++i) acc[i] = sv[0][i];
#pragma unroll
            for (int w = 1; w < 4; ++w) {
#pragma unroll
                for (int i = 0; i < 5; ++i) b[i] = sv[w][i];
                merge5f(acc, b);
            }
            thr = acc[4];   // exact 5th-smallest key
        }

        // ---- Phase B: re-read row (L2/L3-hot), recompute keys, collect ----
        int cntB = 0;  // wave-uniform running count of ==thr matches
#pragma unroll 1
        for (int half = 0; half < 4; ++half) {
            float4 dd[4]; float4 pq[4];
#pragma unroll
            for (int g = 0; g < 4; ++g) {
                const int vi = (half * 4 + g) * 256 + tid;
                dd[g] = dvec[vi];
                pq[g] = pen4[vi];
            }
#pragma unroll
            for (int g = 0; g < 4; ++g) {
                float kk4[4];
                kk4[0] = fminf(dd[g].x, BIGF) + pq[g].x;   // bit-identical to A
                kk4[1] = fminf(dd[g].y, BIGF) + pq[g].y;
                kk4[2] = fminf(dd[g].z, BIGF) + pq[g].z;
                kk4[3] = fminf(dd[g].w, BIGF) + pq[g].w;
                const int G = half * 4 + g;
#pragma unroll
                for (int j = 0; j < 4; ++j) {
                    const float kk = kk4[j];
                    const u64 bb = __ballot(kk <= thr);
                    if (bb) {                              // rare (~6 hits/row)
                        const u64 bA = __ballot(kk < thr);
                        const u64 bB = bb & ~bA;
                        if (kk <= thr) {
                            const unsigned idx =
                                (unsigned)((G * 256 + tid) * 4 + j);
                            if (kk < thr) {                // tier A: exact
                                const int s = atomicAdd(&ldsAcnt, 1);
                                if (s < 8)
                                    ldsA[s] = ((u64)__float_as_uint(kk) << 32)
                                              | (u64)idx;
                            } else {                       // tier B: ==thr
                                const int s = cntB + (int)__popcll(bB & lt_mask);
                                if (s < 8) ldsB[wave][s] = idx;
                            }
                        }
                        cntB += (int)__popcll(bB);
                    }
                }
            }
        }
        if (lane == 0) ldsBcnt[wave] = cntB;
        __syncthreads();

        // ---- exact (key,idx) reconstruction on tid 0 ----
        if (tid == 0) {
            u64 out5[5];
#pragma unroll
            for (int i = 0; i < 5; ++i) out5[i] = 0xFFFFFFFFFFFFFFFFULL;
            const int ca = ldsAcnt < 8 ? ldsAcnt : 8;   // provably <=4
            for (int s = 0; s < ca; ++s) insert64(ldsA[s], out5);
            const u64 thrbits = ((u64)__float_as_uint(thr)) << 32;
            for (int w = 0; w < 4; ++w) {
                const int cb = ldsBcnt[w] < 8 ? ldsBcnt[w] : 8;
                for (int s = 0; s < cb; ++s)
                    insert64(thrbits | (u64)ldsB[w][s], out5);
            }
#pragma unroll
            for (int i = 0; i < 5; ++i)
                wslists[(long long)row * 5 + i] = out5[i];
        }
        __syncthreads();   // LDS reused next row
    }
}

// ---------------------------------------------------------------------------
// Pass 2 (fused): coalesced float4 copy of X->out; the lane owning each
// row's first float4 runs the epilogue (validated rounds 6-9) and patches .x.
// ---------------------------------------------------------------------------
__global__ __launch_bounds__(256) void pass2_kernel(
    const float* __restrict__ X,
    const u64* __restrict__ wslists,
    const void* __restrict__ maskp,
    const void* __restrict__ mkfitp,
    const float* __restrict__ fitX,
    const int* __restrict__ dmap,
    const int* __restrict__ wflagp,
    const float* __restrict__ cmeanp,
    const unsigned char* __restrict__ inmiss,
    const unsigned char* __restrict__ pot8,
    float* __restrict__ out)
{
    const int gid = blockIdx.x * 256 + threadIdx.x;    // 0..32767
    if (gid >= NQ * DD / 4) return;
    float4 v4 = ((const float4*)X)[gid];

    if ((gid & 7) == 0) {
        const int r = gid >> 3;
        const int q = dmap[r];
        u64 v[5];
        const u64* lp = wslists + (long long)q * 5;
#pragma unroll
        for (int i = 0; i < 5; ++i) v[i] = lp[i];

        const int w32 = *wflagp;
        const bool has_valid = (unsigned)(v[0] >> 32) < __float_as_uint(BIGF);
        const bool receiver =
            inmiss[r] && boolat(maskp, (long long)r * DD + COLIDX, w32);

        float val;
        if (!receiver) {
            val = v4.x;                    // X[r*DD+0]
        } else if (!has_valid) {
            val = *cmeanp;
        } else {
            float keyf[5]; bool ok[5]; int idxc[5];
#pragma unroll
            for (int i = 0; i < 5; ++i) {
                keyf[i] = __uint_as_float((unsigned)(v[i] >> 32));
                const unsigned id = (unsigned)(v[i] & 0xFFFFFFFFu);
                ok[i] = id < NT;
                idxc[i] = ok[i] ? (int)id : 0;
            }
            float dnr[5]; int mfv[5]; unsigned char vldb[5];
#pragma unroll
            for (int i = 0; i < 5; ++i)
                dnr[i] = fitX[(long long)idxc[i] * DD + COLIDX];
#pragma unroll
            for (int i = 0; i < 5; ++i)
                mfv[i] = boolat(mkfitp, (long long)idxc[i] * DD + COLIDX, w32);
#pragma unroll
            for (int i = 0; i < 5; ++i) vldb[i] = pot8[idxc[i]];

            float wk[5];
            bool infrow = false;
#pragma unroll
            for (int i = 0; i < 5; ++i) {
                const float dpot = (keyf[i] == BIGF) ? __builtin_nanf("") : keyf[i];
                const float t = 1.0f / dpot;     // 0->inf, inf->0, NaN->NaN
                wk[i] = ok[i] ? t : 0.0f;
                if (ok[i] && isinf(t)) infrow = true;
            }
            if (infrow) {
#pragma unroll
                for (int i = 0; i < 5; ++i) wk[i] = isinf(wk[i]) ? 1.0f : 0.0f;
            }
#pragma unroll
            for (int i = 0; i < 5; ++i) if (wk[i] != wk[i]) wk[i] = 0.0f;

            float wsum = 0.0f, vsum = 0.0f;
#pragma unroll
            for (int i = 0; i < 5; ++i) {
                const float dm = ok[i] ? (1.0f - (float)mfv[i]) : 0.0f;
                const float vl = ok[i] ? (float)vldb[i] : 0.0f;
                const float nw = dm * wk[i] * vl;
                wsum += nw;
                vsum += dnr[i] * nw;
            }
            const float div = (wsum == 0.0f) ? 1.0f : wsum;
            val = vsum / div;
        }
        v4.x = val;
    }
    ((float4*)out)[gid] = v4;
}

extern "C" void kernel_launch(void* const* d_in, const int* in_sizes, int n_in,
                              void* d_out, int out_size, void* d_ws, size_t ws_size,
                              hipStream_t stream) {
    const float* X     = (const float*)d_in[0];
    const float* dist  = (const float*)d_in[1];
    const void*  nm    = d_in[2];   // non_missing_fix_X (bool)
    const void*  mkfit = d_in[3];   // mask_fit_X (bool)
    const int*   dmap  = (const int*)d_in[4];
    const void*  maskp = d_in[5];   // mask (bool)
    const int*   rmi   = (const int*)d_in[6];
    const float* fitX  = (const float*)d_in[7];
    float* out = (float*)d_out;

    // workspace layout (all 4-byte aligned)
    u64*   wslists = (u64*)d_ws;                               // 4096*40 B
    char*  base    = (char*)d_ws + (size_t)NQ * 5 * 8;
    int*   wflag   = (int*)base;
    float* cmean   = (float*)(base + 4);
    float* partial = (float*)(base + 8);                       // 512 B
    unsigned char* inmiss = (unsigned char*)base + 520;        // NQ bytes
    unsigned char* pot8   = (unsigned char*)base + 520 + NQ;   // NT bytes
    float* pen = (float*)(base + 520 + NQ + NT);               // NT floats (64 KB)

    prep1_kernel<<<64, 256, 0, stream>>>(nm, mkfit, fitX, wflag, partial,
                                         inmiss, pot8, pen);
    prep2_kernel<<<1, 256, 0, stream>>>(rmi, partial, cmean, inmiss);
    pass1_kernel<<<P1_BLOCKS, 256, 0, stream>>>(dist, pen, wslists);
    pass2_kernel<<<(NQ * DD / 4 + 255) / 256, 256, 0, stream>>>(
        X, wslists, maskp, mkfit, fitX, dmap, wflag, cmean, inmiss, pot8, out);
}

// Round 11
// 134.768 us; speedup vs baseline: 3.4015x; 1.2748x over previous
//
#include <hip/hip_runtime.h>
#include <math.h>

#define NQ 4096
#define NT 16384
#define DD 32
#define COLIDX 0
#define BIGF 1.0e10f
#define INFF __builtin_inff()

typedef unsigned long long u64;

#define ROW_VECS (NT / 4)                 // 4096 float4 per row
#define ROWS_PER_BLOCK 2
#define P1_BLOCKS (NQ / ROWS_PER_BLOCK)   // 2048 blocks, fully resident

// ---------------------------------------------------------------------------
// bool-width helpers (unknown numpy bool storage: u8 vs i32)
// ---------------------------------------------------------------------------
__device__ __forceinline__ int boolat(const void* p, long long idx, int w32) {
    if (w32) return ((const int*)p)[idx] != 0;
    return ((const unsigned char*)p)[idx] != 0;
}

__device__ __forceinline__ int detect_w32(const void* nm, const void* mk,
                                          int tid, int* s_bad) {
    if (tid == 0) *s_bad = 0;
    __syncthreads();
    const unsigned char* nm8 = (const unsigned char*)nm;
    const unsigned char* mk8 = (const unsigned char*)mk;
    int bad = 0;
    for (int b = tid; b < 4096; b += 256)
        if ((int)nm8[b] + (int)mk8[b] != 1) bad = 1;
    if (bad) atomicOr(s_bad, 1);
    __syncthreads();
    return *s_bad ? 1 : 0;
}

// ---------------------------------------------------------------------------
// prep1: 64 blocks x 256 threads — pot8 + pen pack, colmean partials,
// inmiss clear.
// ---------------------------------------------------------------------------
__global__ __launch_bounds__(256) void prep1_kernel(
    const void* __restrict__ nm, const void* __restrict__ mk,
    const float* __restrict__ fitX,
    int* __restrict__ wflag, float* __restrict__ partial,
    unsigned char* __restrict__ inmiss, unsigned char* __restrict__ pot8,
    float* __restrict__ pen)
{
    __shared__ int s_bad;
    __shared__ float sc[256], sm[256];
    const int tid = threadIdx.x;
    const int w32 = detect_w32(nm, mk, tid, &s_bad);
    if (blockIdx.x == 0 && tid == 0) *wflag = w32;

    const int t = blockIdx.x * 256 + tid;          // 0..16383
    const int pot = boolat(nm, (long long)t * DD + COLIDX, w32);
    pot8[t] = (unsigned char)pot;
    pen[t]  = pot ? 0.0f : INFF;

    float cs = 0.0f, ms = 0.0f;
    if (!boolat(mk, (long long)t * DD + COLIDX, w32)) {
        cs = fitX[(long long)t * DD + COLIDX];
        ms = 1.0f;
    }
    sc[tid] = cs; sm[tid] = ms;
    __syncthreads();
#pragma unroll
    for (int s = 128; s > 0; s >>= 1) {
        if (tid < s) { sc[tid] += sc[tid + s]; sm[tid] += sm[tid + s]; }
        __syncthreads();
    }
    if (tid == 0) { partial[blockIdx.x * 2] = sc[0]; partial[blockIdx.x * 2 + 1] = sm[0]; }

    if (t < NQ) inmiss[t] = 0;
}

__global__ __launch_bounds__(256) void prep2_kernel(
    const int* __restrict__ rmi, const float* __restrict__ partial,
    float* __restrict__ cmean, unsigned char* __restrict__ inmiss)
{
    const int tid = threadIdx.x;
    for (int i = tid; i < NQ; i += 256) {
        int r = rmi[i];
        if (r >= 0 && r < NQ) inmiss[r] = 1;
    }
    if (tid == 0) {
        float c = 0.0f, m = 0.0f;
        for (int b = 0; b < 64; ++b) { c += partial[2 * b]; m += partial[2 * b + 1]; }
        *cmean = c / (m > 0.0f ? m : 1.0f);
    }
}

// ---------------------------------------------------------------------------
// f32 key-only network primitives (keys never NaN: fmin removes NaN, +pen
// keeps finite/INF). casf = v_min + v_max = 2 VALU.
// ---------------------------------------------------------------------------
__device__ __forceinline__ void casf(float& x, float& y) {
    const float lo = fminf(x, y);
    const float hi = fmaxf(x, y);
    x = lo; y = hi;
}

// Merge ascending sorted-5 'a' with sorted-5 'b', keep lowest 5 (validated).
__device__ __forceinline__ void merge5f(float a[5], const float b[5]) {
    float m0 = fminf(a[0], b[4]);
    float m1 = fminf(a[1], b[3]);
    float m2 = fminf(a[2], b[2]);
    float m3 = fminf(a[3], b[1]);
    float m4 = fminf(a[4], b[0]);
    casf(m0, m4);
    casf(m1, m3); casf(m2, m4);
    casf(m1, m2); casf(m3, m4);
    a[0] = m0; a[1] = m1; a[2] = m2; a[3] = m3; a[4] = m4;
}

// exact u64 (key,idx) insert — used only on the tiny candidate tail
__device__ __forceinline__ void insert64(u64 k, u64 v[5]) {
    const bool c0 = k < v[0];
    const bool c1 = k < v[1];
    const bool c2 = k < v[2];
    const bool c3 = k < v[3];
    const bool c4 = k < v[4];
    v[4] = c4 ? (c3 ? v[3] : k) : v[4];
    v[3] = c3 ? (c2 ? v[2] : k) : v[3];
    v[2] = c2 ? (c1 ? v[1] : k) : v[2];
    v[1] = c1 ? (c0 ? v[0] : k) : v[1];
    v[0] = c0 ? k : v[0];
}

// ---------------------------------------------------------------------------
// Pass 1: 2 rows per block, 2048 blocks. __launch_bounds__(256,4) caps VGPR
// at 128 (round-10 lesson: unhinted, the compiler allocated 256 VGPR ->
// 11% occupancy -> latency-bound). Live set ~60 VGPR -> no spill expected.
// Phase A: f32-key scan (sort4 + merge-5 networks) -> exact 5th key thr.
// Phase B: re-read row (L2/L3-hot), recompute keys bit-identically, collect
//   tier A (k<thr, exact) + tier B (k==thr, idx-ordered, cap 8).
// tid0 rebuilds exact (key,idx) top-5, writes 5 u64/row (validated r9/r10).
// ---------------------------------------------------------------------------
__global__ __launch_bounds__(256, 4) void pass1_kernel(
    const float* __restrict__ dist,
    const float* __restrict__ pen,
    u64* __restrict__ wslists)
{
    __shared__ float sv[4][5];
    __shared__ u64 ldsA[8];
    __shared__ unsigned ldsB[4][8];
    __shared__ int ldsAcnt;
    __shared__ int ldsBcnt[4];

    const int tid  = threadIdx.x;
    const int lane = tid & 63;
    const int wave = tid >> 6;
    const u64 lt_mask = (lane == 0) ? 0ull : (~0ull >> (64 - lane));
    const float4* pen4 = (const float4*)pen;

#pragma unroll 1
    for (int rr = 0; rr < ROWS_PER_BLOCK; ++rr) {
        const int row = blockIdx.x * ROWS_PER_BLOCK + rr;
        const float4* dvec = (const float4*)dist + (long long)row * ROW_VECS;

        if (tid == 0) ldsAcnt = 0;
        if (tid < 4) ldsBcnt[tid] = 0;

        float v[5];
#pragma unroll
        for (int i = 0; i < 5; ++i) v[i] = INFF;

        // ---- Phase A: scan; keys NOT stored (recomputed in phase B) ----
#pragma unroll 1
        for (int half = 0; half < 4; ++half) {
            float4 dd[4]; float4 pq[4];
#pragma unroll
            for (int g = 0; g < 4; ++g) {
                const int vi = (half * 4 + g) * 256 + tid;
                dd[g] = dvec[vi];
                pq[g] = pen4[vi];
            }
#pragma unroll
            for (int g = 0; g < 4; ++g) {
                float s0 = fminf(dd[g].x, BIGF) + pq[g].x;  // NaN->BIG; !pot->INF
                float s1 = fminf(dd[g].y, BIGF) + pq[g].y;
                float s2 = fminf(dd[g].z, BIGF) + pq[g].z;
                float s3 = fminf(dd[g].w, BIGF) + pq[g].w;
                // sort4: (0,1)(2,3)(0,2)(1,3)(1,2)
                casf(s0, s1); casf(s2, s3);
                casf(s0, s2); casf(s1, s3);
                casf(s1, s2);
                // merge sorted-4 (MAX pad) into running sorted-5
                float m0 = v[0];
                float m1 = fminf(v[1], s3);
                float m2 = fminf(v[2], s2);
                float m3 = fminf(v[3], s1);
                float m4 = fminf(v[4], s0);
                casf(m0, m4);
                casf(m1, m3); casf(m2, m4);
                casf(m1, m2); casf(m3, m4);
                v[0] = m0; v[1] = m1; v[2] = m2; v[3] = m3; v[4] = m4;
            }
        }

        // ---- wave butterfly (f32) ----
#pragma unroll
        for (int mask = 1; mask <= 32; mask <<= 1) {
            float b[5];
#pragma unroll
            for (int i = 0; i < 5; ++i) b[i] = __shfl_xor(v[i], mask, 64);
            merge5f(v, b);
        }
        if (lane == 0) {
#pragma unroll
            for (int i = 0; i < 5; ++i) sv[wave][i] = v[i];
        }
        __syncthreads();
        float thr;
        {
            float acc[5], b[5];
#pragma unroll
            for (int i = 0; i < 5; ++i) acc[i] = sv[0][i];
#pragma unroll
            for (int w = 1; w < 4; ++w) {
#pragma unroll
                for (int i = 0; i < 5; ++i) b[i] = sv[w][i];
                merge5f(acc, b);
            }
            thr = acc[4];   // exact 5th-smallest key
        }

        // ---- Phase B: re-read row (L2/L3-hot), recompute keys, collect ----
        int cntB = 0;  // wave-uniform running count of ==thr matches
#pragma unroll 1
        for (int half = 0; half < 4; ++half) {
            float4 dd[4]; float4 pq[4];
#pragma unroll
            for (int g = 0; g < 4; ++g) {
                const int vi = (half * 4 + g) * 256 + tid;
                dd[g] = dvec[vi];
                pq[g] = pen4[vi];
            }
#pragma unroll
            for (int g = 0; g < 4; ++g) {
                float kk4[4];
                kk4[0] = fminf(dd[g].x, BIGF) + pq[g].x;   // bit-identical to A
                kk4[1] = fminf(dd[g].y, BIGF) + pq[g].y;
                kk4[2] = fminf(dd[g].z, BIGF) + pq[g].z;
                kk4[3] = fminf(dd[g].w, BIGF) + pq[g].w;
                const int G = half * 4 + g;
#pragma unroll
                for (int j = 0; j < 4; ++j) {
                    const float kk = kk4[j];
                    const u64 bb = __ballot(kk <= thr);
                    if (bb) {                              // rare (~6 hits/row)
                        const u64 bA = __ballot(kk < thr);
                        const u64 bB = bb & ~bA;
                        if (kk <= thr) {
                            const unsigned idx =
                                (unsigned)((G * 256 + tid) * 4 + j);
                            if (kk < thr) {                // tier A: exact
                                const int s = atomicAdd(&ldsAcnt, 1);
                                if (s < 8)
                                    ldsA[s] = ((u64)__float_as_uint(kk) << 32)
                                              | (u64)idx;
                            } else {                       // tier B: ==thr
                                const int s = cntB + (int)__popcll(bB & lt_mask);
                                if (s < 8) ldsB[wave][s] = idx;
                            }
                        }
                        cntB += (int)__popcll(bB);
                    }
                }
            }
        }
        if (lane == 0) ldsBcnt[wave] = cntB;
        __syncthreads();

        // ---- exact (key,idx) reconstruction on tid 0 ----
        if (tid == 0) {
            u64 out5[5];
#pragma unroll
            for (int i = 0; i < 5; ++i) out5[i] = 0xFFFFFFFFFFFFFFFFULL;
            const int ca = ldsAcnt < 8 ? ldsAcnt : 8;   // provably <=4
            for (int s = 0; s < ca; ++s) insert64(ldsA[s], out5);
            const u64 thrbits = ((u64)__float_as_uint(thr)) << 32;
            for (int w = 0; w < 4; ++w) {
                const int cb = ldsBcnt[w] < 8 ? ldsBcnt[w] : 8;
                for (int s = 0; s < cb; ++s)
                    insert64(thrbits | (u64)ldsB[w][s], out5);
            }
#pragma unroll
            for (int i = 0; i < 5; ++i)
                wslists[(long long)row * 5 + i] = out5[i];
        }
        __syncthreads();   // LDS reused next row
    }
}

// ---------------------------------------------------------------------------
// Pass 2 (fused): coalesced float4 copy of X->out; the lane owning each
// row's first float4 runs the epilogue (validated rounds 6-10) and patches .x.
// ---------------------------------------------------------------------------
__global__ __launch_bounds__(256) void pass2_kernel(
    const float* __restrict__ X,
    const u64* __restrict__ wslists,
    const void* __restrict__ maskp,
    const void* __restrict__ mkfitp,
    const float* __restrict__ fitX,
    const int* __restrict__ dmap,
    const int* __restrict__ wflagp,
    const float* __restrict__ cmeanp,
    const unsigned char* __restrict__ inmiss,
    const unsigned char* __restrict__ pot8,
    float* __restrict__ out)
{
    const int gid = blockIdx.x * 256 + threadIdx.x;    // 0..32767
    if (gid >= NQ * DD / 4) return;
    float4 v4 = ((const float4*)X)[gid];

    if ((gid & 7) == 0) {
        const int r = gid >> 3;
        const int q = dmap[r];
        u64 v[5];
        const u64* lp = wslists + (long long)q * 5;
#pragma unroll
        for (int i = 0; i < 5; ++i) v[i] = lp[i];

        const int w32 = *wflagp;
        const bool has_valid = (unsigned)(v[0] >> 32) < __float_as_uint(BIGF);
        const bool receiver =
            inmiss[r] && boolat(maskp, (long long)r * DD + COLIDX, w32);

        float val;
        if (!receiver) {
            val = v4.x;                    // X[r*DD+0]
        } else if (!has_valid) {
            val = *cmeanp;
        } else {
            float keyf[5]; bool ok[5]; int idxc[5];
#pragma unroll
            for (int i = 0; i < 5; ++i) {
                keyf[i] = __uint_as_float((unsigned)(v[i] >> 32));
                const unsigned id = (unsigned)(v[i] & 0xFFFFFFFFu);
                ok[i] = id < NT;
                idxc[i] = ok[i] ? (int)id : 0;
            }
            float dnr[5]; int mfv[5]; unsigned char vldb[5];
#pragma unroll
            for (int i = 0; i < 5; ++i)
                dnr[i] = fitX[(long long)idxc[i] * DD + COLIDX];
#pragma unroll
            for (int i = 0; i < 5; ++i)
                mfv[i] = boolat(mkfitp, (long long)idxc[i] * DD + COLIDX, w32);
#pragma unroll
            for (int i = 0; i < 5; ++i) vldb[i] = pot8[idxc[i]];

            float wk[5];
            bool infrow = false;
#pragma unroll
            for (int i = 0; i < 5; ++i) {
                const float dpot = (keyf[i] == BIGF) ? __builtin_nanf("") : keyf[i];
                const float t = 1.0f / dpot;     // 0->inf, inf->0, NaN->NaN
                wk[i] = ok[i] ? t : 0.0f;
                if (ok[i] && isinf(t)) infrow = true;
            }
            if (infrow) {
#pragma unroll
                for (int i = 0; i < 5; ++i) wk[i] = isinf(wk[i]) ? 1.0f : 0.0f;
            }
#pragma unroll
            for (int i = 0; i < 5; ++i) if (wk[i] != wk[i]) wk[i] = 0.0f;

            float wsum = 0.0f, vsum = 0.0f;
#pragma unroll
            for (int i = 0; i < 5; ++i) {
                const float dm = ok[i] ? (1.0f - (float)mfv[i]) : 0.0f;
                const float vl = ok[i] ? (float)vldb[i] : 0.0f;
                const float nw = dm * wk[i] * vl;
                wsum += nw;
                vsum += dnr[i] * nw;
            }
            const float div = (wsum == 0.0f) ? 1.0f : wsum;
            val = vsum / div;
        }
        v4.x = val;
    }
    ((float4*)out)[gid] = v4;
}

extern "C" void kernel_launch(void* const* d_in, const int* in_sizes, int n_in,
                              void* d_out, int out_size, void* d_ws, size_t ws_size,
                              hipStream_t stream) {
    const float* X     = (const float*)d_in[0];
    const float* dist  = (const float*)d_in[1];
    const void*  nm    = d_in[2];   // non_missing_fix_X (bool)
    const void*  mkfit = d_in[3];   // mask_fit_X (bool)
    const int*   dmap  = (const int*)d_in[4];
    const void*  maskp = d_in[5];   // mask (bool)
    const int*   rmi   = (const int*)d_in[6];
    const float* fitX  = (const float*)d_in[7];
    float* out = (float*)d_out;

    // workspace layout (all 4-byte aligned)
    u64*   wslists = (u64*)d_ws;                               // 4096*40 B
    char*  base    = (char*)d_ws + (size_t)NQ * 5 * 8;
    int*   wflag   = (int*)base;
    float* cmean   = (float*)(base + 4);
    float* partial = (float*)(base + 8);                       // 512 B
    unsigned char* inmiss = (unsigned char*)base + 520;        // NQ bytes
    unsigned char* pot8   = (unsigned char*)base + 520 + NQ;   // NT bytes
    float* pen = (float*)(base + 520 + NQ + NT);               // NT floats (64 KB)

    prep1_kernel<<<64, 256, 0, stream>>>(nm, mkfit, fitX, wflag, partial,
                                         inmiss, pot8, pen);
    prep2_kernel<<<1, 256, 0, stream>>>(rmi, partial, cmean, inmiss);
    pass1_kernel<<<P1_BLOCKS, 256, 0, stream>>>(dist, pen, wslists);
    pass2_kernel<<<(NQ * DD / 4 + 255) / 256, 256, 0, stream>>>(
        X, wslists, maskp, mkfit, fitX, dmap, wflag, cmean, inmiss, pot8, out);
}

// Round 12
// 87.935 us; speedup vs baseline: 5.2131x; 1.5326x over previous
//
#include <hip/hip_runtime.h>
#include <math.h>

#define NQ 4096
#define NT 16384
#define DD 32
#define COLIDX 0
#define BIGF 1.0e10f
#define INFF __builtin_inff()

typedef unsigned long long u64;

#define ROW_VECS (NT / 4)                 // 4096 float4 per row
#define ROWS_PER_BLOCK 2
#define P1_BLOCKS (NQ / ROWS_PER_BLOCK)   // 2048 blocks = 8 blocks/CU

// ---------------------------------------------------------------------------
// bool-width helpers (unknown numpy bool storage: u8 vs i32)
// ---------------------------------------------------------------------------
__device__ __forceinline__ int boolat(const void* p, long long idx, int w32) {
    if (w32) return ((const int*)p)[idx] != 0;
    return ((const unsigned char*)p)[idx] != 0;
}

__device__ __forceinline__ int detect_w32(const void* nm, const void* mk,
                                          int tid, int* s_bad) {
    if (tid == 0) *s_bad = 0;
    __syncthreads();
    const unsigned char* nm8 = (const unsigned char*)nm;
    const unsigned char* mk8 = (const unsigned char*)mk;
    int bad = 0;
    for (int b = tid; b < 4096; b += 256)
        if ((int)nm8[b] + (int)mk8[b] != 1) bad = 1;
    if (bad) atomicOr(s_bad, 1);
    __syncthreads();
    return *s_bad ? 1 : 0;
}

// ---------------------------------------------------------------------------
// prep1: 64 blocks x 256 threads — pot8 pack, colmean partials, inmiss clear.
// (validated rounds 2-11)
// ---------------------------------------------------------------------------
__global__ __launch_bounds__(256) void prep1_kernel(
    const void* __restrict__ nm, const void* __restrict__ mk,
    const float* __restrict__ fitX,
    int* __restrict__ wflag, float* __restrict__ partial,
    unsigned char* __restrict__ inmiss, unsigned char* __restrict__ pot8)
{
    __shared__ int s_bad;
    __shared__ float sc[256], sm[256];
    const int tid = threadIdx.x;
    const int w32 = detect_w32(nm, mk, tid, &s_bad);
    if (blockIdx.x == 0 && tid == 0) *wflag = w32;

    const int t = blockIdx.x * 256 + tid;          // 0..16383
    pot8[t] = (unsigned char)boolat(nm, (long long)t * DD + COLIDX, w32);

    float cs = 0.0f, ms = 0.0f;
    if (!boolat(mk, (long long)t * DD + COLIDX, w32)) {
        cs = fitX[(long long)t * DD + COLIDX];
        ms = 1.0f;
    }
    sc[tid] = cs; sm[tid] = ms;
    __syncthreads();
#pragma unroll
    for (int s = 128; s > 0; s >>= 1) {
        if (tid < s) { sc[tid] += sc[tid + s]; sm[tid] += sm[tid + s]; }
        __syncthreads();
    }
    if (tid == 0) { partial[blockIdx.x * 2] = sc[0]; partial[blockIdx.x * 2 + 1] = sm[0]; }

    if (t < NQ) inmiss[t] = 0;
}

__global__ __launch_bounds__(256) void prep2_kernel(
    const int* __restrict__ rmi, const float* __restrict__ partial,
    float* __restrict__ cmean, unsigned char* __restrict__ inmiss)
{
    const int tid = threadIdx.x;
    for (int i = tid; i < NQ; i += 256) {
        int r = rmi[i];
        if (r >= 0 && r < NQ) inmiss[r] = 1;
    }
    if (tid == 0) {
        float c = 0.0f, m = 0.0f;
        for (int b = 0; b < 64; ++b) { c += partial[2 * b]; m += partial[2 * b + 1]; }
        *cmean = c / (m > 0.0f ? m : 1.0f);
    }
}

// ---------------------------------------------------------------------------
// packed-u64 primitives. key64 = (float_bits << 32) | idx. Positive-float
// bit order == numeric order -> u64 asc == (key asc, idx asc) == exact
// jax.lax.top_k tie-break (validated rounds 6-8, absmax 0).
// ---------------------------------------------------------------------------
__device__ __forceinline__ u64 u64min(u64 a, u64 b) { return (b < a) ? b : a; }

__device__ __forceinline__ void cas64(u64& x, u64& y) {
    const bool c = y < x;
    const u64 lo = c ? y : x;
    const u64 hi = c ? x : y;
    x = lo; y = hi;
}

// key: pot ? (NaN ? BIGF : d) : +inf.  fminf(NaN, BIGF) == BIGF.
__device__ __forceinline__ u64 mkkey(float d, unsigned char p, unsigned idx) {
    const float key = (p != 0) ? fminf(d, BIGF) : INFF;
    return ((u64)__float_as_uint(key) << 32) | (u64)idx;
}

// Merge two ascending sorted-5 lists, keep lowest 5, output sorted.
// Half-cleaner -> mountain -> pruned bitonic cleanup (validated rounds 6-8).
__device__ __forceinline__ void merge_sorted5(u64 a[5], const u64 b[5]) {
    u64 m0 = u64min(a[0], b[4]);
    u64 m1 = u64min(a[1], b[3]);
    u64 m2 = u64min(a[2], b[2]);
    u64 m3 = u64min(a[3], b[1]);
    u64 m4 = u64min(a[4], b[0]);
    cas64(m0, m4);
    cas64(m1, m3); cas64(m2, m4);
    cas64(m1, m2); cas64(m3, m4);
    a[0] = m0; a[1] = m1; a[2] = m2; a[3] = m3; a[4] = m4;
}

__device__ __forceinline__ u64 shflx64(u64 x, int mask) {
    const int lo = __shfl_xor((int)(unsigned)x, mask, 64);
    const int hi = __shfl_xor((int)(unsigned)(x >> 32), mask, 64);
    return ((u64)(unsigned)hi << 32) | (u64)(unsigned)lo;
}

// ---------------------------------------------------------------------------
// Pass 1: single-pass u64 (round-8 structure — the empirically fastest),
// 2 rows per block (2048 blocks: clears the ~64 blocks/us dispatch floor
// that pinned round 8's 4096 blocks at ~64 us, and gives 8 blocks/CU =
// 32 waves/CU max TLP). __launch_bounds__(256,8) pins VGPR <= 64; live set
// counted ~52 (16 dist + 4 pot staging + 10 acc + temps) -> no spill.
// No phase B, no re-read: exact (key,idx) carried through the networks.
// ---------------------------------------------------------------------------
__global__ __launch_bounds__(256, 8) void pass1_kernel(
    const float* __restrict__ dist,
    const unsigned char* __restrict__ pot8,
    u64* __restrict__ wslists)
{
    __shared__ u64 sv[3][5];
    const int tid = threadIdx.x;
    const uchar4* pvec = (const uchar4*)pot8;

#pragma unroll 1
    for (int rr = 0; rr < ROWS_PER_BLOCK; ++rr) {
        const int row = blockIdx.x * ROWS_PER_BLOCK + rr;
        const float4* dvec = (const float4*)dist + (long long)row * ROW_VECS;

        u64 v[5];
#pragma unroll
        for (int k = 0; k < 5; ++k) v[k] = 0xFFFFFFFFFFFFFFFFULL;

#pragma unroll 1
        for (int half = 0; half < 4; ++half) {
            // batch 8 independent loads (4 dist float4 + 4 pot uchar4)
            float4 dd[4]; uchar4 pp[4];
#pragma unroll
            for (int g = 0; g < 4; ++g) {
                const int vi = (half * 4 + g) * 256 + tid;
                dd[g] = dvec[vi];
                pp[g] = pvec[vi];
            }
#pragma unroll
            for (int g = 0; g < 4; ++g) {
                const unsigned base =
                    (unsigned)(((half * 4 + g) * 256 + tid) * 4);
                u64 s0 = mkkey(dd[g].x, pp[g].x, base + 0);
                u64 s1 = mkkey(dd[g].y, pp[g].y, base + 1);
                u64 s2 = mkkey(dd[g].z, pp[g].z, base + 2);
                u64 s3 = mkkey(dd[g].w, pp[g].w, base + 3);
                // sort4: (0,1)(2,3)(0,2)(1,3)(1,2)
                cas64(s0, s1); cas64(s2, s3);
                cas64(s0, s2); cas64(s1, s3);
                cas64(s1, s2);
                // merge sorted-4 (MAX pad) into running sorted-5
                u64 m0 = v[0];
                u64 m1 = u64min(v[1], s3);
                u64 m2 = u64min(v[2], s2);
                u64 m3 = u64min(v[3], s1);
                u64 m4 = u64min(v[4], s0);
                cas64(m0, m4);
                cas64(m1, m3); cas64(m2, m4);
                cas64(m1, m2); cas64(m3, m4);
                v[0] = m0; v[1] = m1; v[2] = m2; v[3] = m3; v[4] = m4;
            }
        }

        // 6-stage butterfly across the wave (validated)
#pragma unroll
        for (int mask = 1; mask <= 32; mask <<= 1) {
            u64 b[5];
#pragma unroll
            for (int k = 0; k < 5; ++k) b[k] = shflx64(v[k], mask);
            merge_sorted5(v, b);
        }

        // cross-wave via LDS; tid 0 finalizes
        const int wave = tid >> 6;
        if (wave > 0 && (tid & 63) == 0) {
#pragma unroll
            for (int k = 0; k < 5; ++k) sv[wave - 1][k] = v[k];
        }
        __syncthreads();
        if (tid == 0) {
            u64 b[5];
#pragma unroll
            for (int w = 0; w < 3; ++w) {
                b[0] = sv[w][0]; b[1] = sv[w][1]; b[2] = sv[w][2];
                b[3] = sv[w][3]; b[4] = sv[w][4];
                merge_sorted5(v, b);
            }
#pragma unroll
            for (int k = 0; k < 5; ++k)
                wslists[(long long)row * 5 + k] = v[k];
        }
        __syncthreads();   // sv reused next row
    }
}

// ---------------------------------------------------------------------------
// Pass 2 (fused): coalesced float4 copy of X->out; the lane owning each
// row's first float4 runs the epilogue (validated rounds 6-11) and patches .x.
// ---------------------------------------------------------------------------
__global__ __launch_bounds__(256) void pass2_kernel(
    const float* __restrict__ X,
    const u64* __restrict__ wslists,
    const void* __restrict__ maskp,
    const void* __restrict__ mkfitp,
    const float* __restrict__ fitX,
    const int* __restrict__ dmap,
    const int* __restrict__ wflagp,
    const float* __restrict__ cmeanp,
    const unsigned char* __restrict__ inmiss,
    const unsigned char* __restrict__ pot8,
    float* __restrict__ out)
{
    const int gid = blockIdx.x * 256 + threadIdx.x;    // 0..32767
    if (gid >= NQ * DD / 4) return;
    float4 v4 = ((const float4*)X)[gid];

    if ((gid & 7) == 0) {
        const int r = gid >> 3;
        const int q = dmap[r];
        u64 v[5];
        const u64* lp = wslists + (long long)q * 5;
#pragma unroll
        for (int i = 0; i < 5; ++i) v[i] = lp[i];

        const int w32 = *wflagp;
        const bool has_valid = (unsigned)(v[0] >> 32) < __float_as_uint(BIGF);
        const bool receiver =
            inmiss[r] && boolat(maskp, (long long)r * DD + COLIDX, w32);

        float val;
        if (!receiver) {
            val = v4.x;                    // X[r*DD+0]
        } else if (!has_valid) {
            val = *cmeanp;
        } else {
            float keyf[5]; bool ok[5]; int idxc[5];
#pragma unroll
            for (int i = 0; i < 5; ++i) {
                keyf[i] = __uint_as_float((unsigned)(v[i] >> 32));
                const unsigned id = (unsigned)(v[i] & 0xFFFFFFFFu);
                ok[i] = id < NT;
                idxc[i] = ok[i] ? (int)id : 0;
            }
            float dnr[5]; int mfv[5]; unsigned char vldb[5];
#pragma unroll
            for (int i = 0; i < 5; ++i)
                dnr[i] = fitX[(long long)idxc[i] * DD + COLIDX];
#pragma unroll
            for (int i = 0; i < 5; ++i)
                mfv[i] = boolat(mkfitp, (long long)idxc[i] * DD + COLIDX, w32);
#pragma unroll
            for (int i = 0; i < 5; ++i) vldb[i] = pot8[idxc[i]];

            float wk[5];
            bool infrow = false;
#pragma unroll
            for (int i = 0; i < 5; ++i) {
                const float dpot = (keyf[i] == BIGF) ? __builtin_nanf("") : keyf[i];
                const float t = 1.0f / dpot;     // 0->inf, inf->0, NaN->NaN
                wk[i] = ok[i] ? t : 0.0f;
                if (ok[i] && isinf(t)) infrow = true;
            }
            if (infrow) {
#pragma unroll
                for (int i = 0; i < 5; ++i) wk[i] = isinf(wk[i]) ? 1.0f : 0.0f;
            }
#pragma unroll
            for (int i = 0; i < 5; ++i) if (wk[i] != wk[i]) wk[i] = 0.0f;

            float wsum = 0.0f, vsum = 0.0f;
#pragma unroll
            for (int i = 0; i < 5; ++i) {
                const float dm = ok[i] ? (1.0f - (float)mfv[i]) : 0.0f;
                const float vl = ok[i] ? (float)vldb[i] : 0.0f;
                const float nw = dm * wk[i] * vl;
                wsum += nw;
                vsum += dnr[i] * nw;
            }
            const float div = (wsum == 0.0f) ? 1.0f : wsum;
            val = vsum / div;
        }
        v4.x = val;
    }
    ((float4*)out)[gid] = v4;
}

extern "C" void kernel_launch(void* const* d_in, const int* in_sizes, int n_in,
                              void* d_out, int out_size, void* d_ws, size_t ws_size,
                              hipStream_t stream) {
    const float* X     = (const float*)d_in[0];
    const float* dist  = (const float*)d_in[1];
    const void*  nm    = d_in[2];   // non_missing_fix_X (bool)
    const void*  mkfit = d_in[3];   // mask_fit_X (bool)
    const int*   dmap  = (const int*)d_in[4];
    const void*  maskp = d_in[5];   // mask (bool)
    const int*   rmi   = (const int*)d_in[6];
    const float* fitX  = (const float*)d_in[7];
    float* out = (float*)d_out;

    // workspace layout (all 4-byte aligned)
    u64*   wslists = (u64*)d_ws;                               // 4096*40 B
    char*  base    = (char*)d_ws + (size_t)NQ * 5 * 8;
    int*   wflag   = (int*)base;
    float* cmean   = (float*)(base + 4);
    float* partial = (float*)(base + 8);                       // 512 B
    unsigned char* inmiss = (unsigned char*)base + 520;        // NQ bytes
    unsigned char* pot8   = (unsigned char*)base + 520 + NQ;   // NT bytes

    prep1_kernel<<<64, 256, 0, stream>>>(nm, mkfit, fitX, wflag, partial,
                                         inmiss, pot8);
    prep2_kernel<<<1, 256, 0, stream>>>(rmi, partial, cmean, inmiss);
    pass1_kernel<<<P1_BLOCKS, 256, 0, stream>>>(dist, pot8, wslists);
    pass2_kernel<<<(NQ * DD / 4 + 255) / 256, 256, 0, stream>>>(
        X, wslists, maskp, mkfit, fitX, dmap, wflag, cmean, inmiss, pot8, out);
}

// Round 13
// 67.443 us; speedup vs baseline: 6.7971x; 1.3038x over previous
//
#include <hip/hip_runtime.h>
#include <math.h>

#define NQ 4096
#define NT 16384
#define DD 32
#define COLIDX 0
#define BIGF 1.0e10f
#define INFF __builtin_inff()

typedef unsigned long long u64;

#define ROW_VECS (NT / 4)                 // 4096 float4 per row
#define ROWS_PER_BLOCK 2
#define P1_BLOCKS (NQ / ROWS_PER_BLOCK)   // 2048 blocks = 8 blocks/CU

// Sentinel: larger (as u64/f64) than any real packed key (max real hi =
// 0x7F800000 = +inf bits, idx <= 16383); valid positive non-NaN f64.
#define SENT_BITS 0x7F800000FFFFFFFFULL

// ---------------------------------------------------------------------------
// bool-width helpers (unknown numpy bool storage: u8 vs i32)
// ---------------------------------------------------------------------------
__device__ __forceinline__ int boolat(const void* p, long long idx, int w32) {
    if (w32) return ((const int*)p)[idx] != 0;
    return ((const unsigned char*)p)[idx] != 0;
}

__device__ __forceinline__ int detect_w32(const void* nm, const void* mk,
                                          int tid, int* s_bad) {
    if (tid == 0) *s_bad = 0;
    __syncthreads();
    const unsigned char* nm8 = (const unsigned char*)nm;
    const unsigned char* mk8 = (const unsigned char*)mk;
    int bad = 0;
    for (int b = tid; b < 4096; b += 256)
        if ((int)nm8[b] + (int)mk8[b] != 1) bad = 1;
    if (bad) atomicOr(s_bad, 1);
    __syncthreads();
    return *s_bad ? 1 : 0;
}

// ---------------------------------------------------------------------------
// prep1: 64 blocks x 256 threads — pot8 pack, colmean partials, inmiss clear.
// (validated rounds 2-12)
// ---------------------------------------------------------------------------
__global__ __launch_bounds__(256) void prep1_kernel(
    const void* __restrict__ nm, const void* __restrict__ mk,
    const float* __restrict__ fitX,
    int* __restrict__ wflag, float* __restrict__ partial,
    unsigned char* __restrict__ inmiss, unsigned char* __restrict__ pot8)
{
    __shared__ int s_bad;
    __shared__ float sc[256], sm[256];
    const int tid = threadIdx.x;
    const int w32 = detect_w32(nm, mk, tid, &s_bad);
    if (blockIdx.x == 0 && tid == 0) *wflag = w32;

    const int t = blockIdx.x * 256 + tid;          // 0..16383
    pot8[t] = (unsigned char)boolat(nm, (long long)t * DD + COLIDX, w32);

    float cs = 0.0f, ms = 0.0f;
    if (!boolat(mk, (long long)t * DD + COLIDX, w32)) {
        cs = fitX[(long long)t * DD + COLIDX];
        ms = 1.0f;
    }
    sc[tid] = cs; sm[tid] = ms;
    __syncthreads();
#pragma unroll
    for (int s = 128; s > 0; s >>= 1) {
        if (tid < s) { sc[tid] += sc[tid + s]; sm[tid] += sm[tid + s]; }
        __syncthreads();
    }
    if (tid == 0) { partial[blockIdx.x * 2] = sc[0]; partial[blockIdx.x * 2 + 1] = sm[0]; }

    if (t < NQ) inmiss[t] = 0;
}

__global__ __launch_bounds__(256) void prep2_kernel(
    const int* __restrict__ rmi, const float* __restrict__ partial,
    float* __restrict__ cmean, unsigned char* __restrict__ inmiss)
{
    const int tid = threadIdx.x;
    for (int i = tid; i < NQ; i += 256) {
        int r = rmi[i];
        if (r >= 0 && r < NQ) inmiss[r] = 1;
    }
    if (tid == 0) {
        float c = 0.0f, m = 0.0f;
        for (int b = 0; b < 64; ++b) { c += partial[2 * b]; m += partial[2 * b + 1]; }
        *cmean = c / (m > 0.0f ? m : 1.0f);
    }
}

// ---------------------------------------------------------------------------
// f64-packed key trick. packed = bits((key_f32_bits << 32) | idx) viewed as
// double. All packed values are POSITIVE NON-NAN f64 (hi word is the bit
// pattern of a positive finite/inf f32: f64 exponent field = key bits
// [30:20], all-ones would require f32 exp 0xFF AND mantissa[22:20]=111,
// i.e. a NaN f32 key — excluded since fminf removes NaN). For positive
// non-NaN f64, numeric order == bit order == our exact (key asc, idx asc)
// jax.lax.top_k order. So v_min_f64 / v_max_f64 (1 inst each) implement
// exact u64-semantics min / CAS — vs 3 / 5 insts for u64 compare+selects.
// ---------------------------------------------------------------------------
__device__ __forceinline__ double mkkeyd(float d, unsigned char p, unsigned idx) {
    const float key = (p != 0) ? fminf(d, BIGF) : INFF;  // NaN->BIG; !pot->INF
    const u64 bits = ((u64)__float_as_uint(key) << 32) | (u64)idx;
    return __longlong_as_double((long long)bits);
}

__device__ __forceinline__ void casd(double& x, double& y) {
    const double lo = fmin(x, y);
    const double hi = fmax(x, y);
    x = lo; y = hi;
}

// Merge two ascending sorted-5 lists, keep lowest 5, output sorted.
// Half-cleaner -> mountain -> pruned bitonic cleanup (network validated
// rounds 6-12; operands now f64 with identical compare semantics).
__device__ __forceinline__ void merge5d(double a[5], const double b[5]) {
    double m0 = fmin(a[0], b[4]);
    double m1 = fmin(a[1], b[3]);
    double m2 = fmin(a[2], b[2]);
    double m3 = fmin(a[3], b[1]);
    double m4 = fmin(a[4], b[0]);
    casd(m0, m4);
    casd(m1, m3); casd(m2, m4);
    casd(m1, m2); casd(m3, m4);
    a[0] = m0; a[1] = m1; a[2] = m2; a[3] = m3; a[4] = m4;
}

// ---------------------------------------------------------------------------
// Pass 1: single-pass (round-12 structure, fastest so far), networks in f64.
// 2 rows/block, 2048 blocks, __launch_bounds__(256,8) (VGPR<=64; live set
// identical to round 12 — f64 = same 2-reg pairs as u64).
// ---------------------------------------------------------------------------
__global__ __launch_bounds__(256, 8) void pass1_kernel(
    const float* __restrict__ dist,
    const unsigned char* __restrict__ pot8,
    u64* __restrict__ wslists)
{
    __shared__ double sv[3][5];
    const int tid = threadIdx.x;
    const uchar4* pvec = (const uchar4*)pot8;
    const double SENT = __longlong_as_double((long long)SENT_BITS);

#pragma unroll 1
    for (int rr = 0; rr < ROWS_PER_BLOCK; ++rr) {
        const int row = blockIdx.x * ROWS_PER_BLOCK + rr;
        const float4* dvec = (const float4*)dist + (long long)row * ROW_VECS;

        double v[5];
#pragma unroll
        for (int k = 0; k < 5; ++k) v[k] = SENT;

#pragma unroll 1
        for (int half = 0; half < 4; ++half) {
            // batch 8 independent loads (4 dist float4 + 4 pot uchar4)
            float4 dd[4]; uchar4 pp[4];
#pragma unroll
            for (int g = 0; g < 4; ++g) {
                const int vi = (half * 4 + g) * 256 + tid;
                dd[g] = dvec[vi];
                pp[g] = pvec[vi];
            }
#pragma unroll
            for (int g = 0; g < 4; ++g) {
                const unsigned base =
                    (unsigned)(((half * 4 + g) * 256 + tid) * 4);
                double s0 = mkkeyd(dd[g].x, pp[g].x, base + 0);
                double s1 = mkkeyd(dd[g].y, pp[g].y, base + 1);
                double s2 = mkkeyd(dd[g].z, pp[g].z, base + 2);
                double s3 = mkkeyd(dd[g].w, pp[g].w, base + 3);
                // sort4: (0,1)(2,3)(0,2)(1,3)(1,2) — keys globally unique,
                // no stability concern
                casd(s0, s1); casd(s2, s3);
                casd(s0, s2); casd(s1, s3);
                casd(s1, s2);
                // merge sorted-4 (SENT pad) into running sorted-5
                double m0 = v[0];
                double m1 = fmin(v[1], s3);
                double m2 = fmin(v[2], s2);
                double m3 = fmin(v[3], s1);
                double m4 = fmin(v[4], s0);
                casd(m0, m4);
                casd(m1, m3); casd(m2, m4);
                casd(m1, m2); casd(m3, m4);
                v[0] = m0; v[1] = m1; v[2] = m2; v[3] = m3; v[4] = m4;
            }
        }

        // 6-stage butterfly across the wave
#pragma unroll
        for (int mask = 1; mask <= 32; mask <<= 1) {
            double b[5];
#pragma unroll
            for (int k = 0; k < 5; ++k) b[k] = __shfl_xor(v[k], mask, 64);
            merge5d(v, b);
        }

        // cross-wave via LDS; tid 0 finalizes
        const int wave = tid >> 6;
        if (wave > 0 && (tid & 63) == 0) {
#pragma unroll
            for (int k = 0; k < 5; ++k) sv[wave - 1][k] = v[k];
        }
        __syncthreads();
        if (tid == 0) {
            double b[5];
#pragma unroll
            for (int w = 0; w < 3; ++w) {
                b[0] = sv[w][0]; b[1] = sv[w][1]; b[2] = sv[w][2];
                b[3] = sv[w][3]; b[4] = sv[w][4];
                merge5d(v, b);
            }
#pragma unroll
            for (int k = 0; k < 5; ++k)
                wslists[(long long)row * 5 + k] =
                    (u64)__double_as_longlong(v[k]);
        }
        __syncthreads();   // sv reused next row
    }
}

// ---------------------------------------------------------------------------
// Pass 2 (fused): coalesced float4 copy of X->out; the lane owning each
// row's first float4 runs the epilogue (validated rounds 6-12) and patches .x.
// ---------------------------------------------------------------------------
__global__ __launch_bounds__(256) void pass2_kernel(
    const float* __restrict__ X,
    const u64* __restrict__ wslists,
    const void* __restrict__ maskp,
    const void* __restrict__ mkfitp,
    const float* __restrict__ fitX,
    const int* __restrict__ dmap,
    const int* __restrict__ wflagp,
    const float* __restrict__ cmeanp,
    const unsigned char* __restrict__ inmiss,
    const unsigned char* __restrict__ pot8,
    float* __restrict__ out)
{
    const int gid = blockIdx.x * 256 + threadIdx.x;    // 0..32767
    if (gid >= NQ * DD / 4) return;
    float4 v4 = ((const float4*)X)[gid];

    if ((gid & 7) == 0) {
        const int r = gid >> 3;
        const int q = dmap[r];
        u64 v[5];
        const u64* lp = wslists + (long long)q * 5;
#pragma unroll
        for (int i = 0; i < 5; ++i) v[i] = lp[i];

        const int w32 = *wflagp;
        const bool has_valid = (unsigned)(v[0] >> 32) < __float_as_uint(BIGF);
        const bool receiver =
            inmiss[r] && boolat(maskp, (long long)r * DD + COLIDX, w32);

        float val;
        if (!receiver) {
            val = v4.x;                    // X[r*DD+0]
        } else if (!has_valid) {
            val = *cmeanp;
        } else {
            float keyf[5]; bool ok[5]; int idxc[5];
#pragma unroll
            for (int i = 0; i < 5; ++i) {
                keyf[i] = __uint_as_float((unsigned)(v[i] >> 32));
                const unsigned id = (unsigned)(v[i] & 0xFFFFFFFFu);
                ok[i] = id < NT;
                idxc[i] = ok[i] ? (int)id : 0;
            }
            float dnr[5]; int mfv[5]; unsigned char vldb[5];
#pragma unroll
            for (int i = 0; i < 5; ++i)
                dnr[i] = fitX[(long long)idxc[i] * DD + COLIDX];
#pragma unroll
            for (int i = 0; i < 5; ++i)
                mfv[i] = boolat(mkfitp, (long long)idxc[i] * DD + COLIDX, w32);
#pragma unroll
            for (int i = 0; i < 5; ++i) vldb[i] = pot8[idxc[i]];

            float wk[5];
            bool infrow = false;
#pragma unroll
            for (int i = 0; i < 5; ++i) {
                const float dpot = (keyf[i] == BIGF) ? __builtin_nanf("") : keyf[i];
                const float t = 1.0f / dpot;     // 0->inf, inf->0, NaN->NaN
                wk[i] = ok[i] ? t : 0.0f;
                if (ok[i] && isinf(t)) infrow = true;
            }
            if (infrow) {
#pragma unroll
                for (int i = 0; i < 5; ++i) wk[i] = isinf(wk[i]) ? 1.0f : 0.0f;
            }
#pragma unroll
            for (int i = 0; i < 5; ++i) if (wk[i] != wk[i]) wk[i] = 0.0f;

            float wsum = 0.0f, vsum = 0.0f;
#pragma unroll
            for (int i = 0; i < 5; ++i) {
                const float dm = ok[i] ? (1.0f - (float)mfv[i]) : 0.0f;
                const float vl = ok[i] ? (float)vldb[i] : 0.0f;
                const float nw = dm * wk[i] * vl;
                wsum += nw;
                vsum += dnr[i] * nw;
            }
            const float div = (wsum == 0.0f) ? 1.0f : wsum;
            val = vsum / div;
        }
        v4.x = val;
    }
    ((float4*)out)[gid] = v4;
}

extern "C" void kernel_launch(void* const* d_in, const int* in_sizes, int n_in,
                              void* d_out, int out_size, void* d_ws, size_t ws_size,
                              hipStream_t stream) {
    const float* X     = (const float*)d_in[0];
    const float* dist  = (const float*)d_in[1];
    const void*  nm    = d_in[2];   // non_missing_fix_X (bool)
    const void*  mkfit = d_in[3];   // mask_fit_X (bool)
    const int*   dmap  = (const int*)d_in[4];
    const void*  maskp = d_in[5];   // mask (bool)
    const int*   rmi   = (const int*)d_in[6];
    const float* fitX  = (const float*)d_in[7];
    float* out = (float*)d_out;

    // workspace layout (all 4-byte aligned)
    u64*   wslists = (u64*)d_ws;                               // 4096*40 B
    char*  base    = (char*)d_ws + (size_t)NQ * 5 * 8;
    int*   wflag   = (int*)base;
    float* cmean   = (float*)(base + 4);
    float* partial = (float*)(base + 8);                       // 512 B
    unsigned char* inmiss = (unsigned char*)base + 520;        // NQ bytes
    unsigned char* pot8   = (unsigned char*)base + 520 + NQ;   // NT bytes

    prep1_kernel<<<64, 256, 0, stream>>>(nm, mkfit, fitX, wflag, partial,
                                         inmiss, pot8);
    prep2_kernel<<<1, 256, 0, stream>>>(rmi, partial, cmean, inmiss);
    pass1_kernel<<<P1_BLOCKS, 256, 0, stream>>>(dist, pot8, wslists);
    pass2_kernel<<<(NQ * DD / 4 + 255) / 256, 256, 0, stream>>>(
        X, wslists, maskp, mkfit, fitX, dmap, wflag, cmean, inmiss, pot8, out);
}